// Round 8
// baseline (189.036 us; speedup 1.0000x reference)
//
#include <hip/hip_runtime.h>

// SmoothL1 (beta=0.5) masked sum reduction, N = 16M fixed.
// sl1 = ad < 0.5 ? d*d : ad - 0.25  (0.5*d*d/0.5 == d*d exactly: pow-2)
// mask: ad >= 1.0f/len; out[0] = sum(mask ? sl1 : 0)
//
// FINAL (R5 structure restored). Session findings:
//  - R1-R3: regular cached loads plateau at 73-78us (2.76 TB/s effective);
//    invariant to MLP (batched, SW-pipelined) and to HBM-vs-L3 sourcing.
//  - R4: __builtin_nontemporal_load -> 49us. Mechanism: streamed-line
//    write-allocation into L2/L3 was stealing read-path service BW.
//  - R5: + persistent blocks & explicit prefetch pipeline -> 47.5us,
//    4.23 TB/s effective read (source-invariant again).
//  - R6: 8192 blocks x 2 iters regressed 2.4x (per-block work too small);
//    keep >=100KB traffic/block.
//  - R7: mixing cached path for lens regressed 13% (allocation pollution
//    is shared-resource; paths don't add).
// Structural ceiling: 201 MB mandatory reads / ~4.23 TB/s nt-read service
// cap (~530 GB/s/XCD, source-invariant) ~= 47.5us floor = this kernel.

#define N_TOTAL 16777216
#define NVEC    (N_TOTAL / 4)       // 4194304 vec4 groups
#define BLOCK   256
#define GRID    2048                // 8 blocks/CU, 32 waves/CU
#define ITERS   (NVEC / (BLOCK * GRID))   // 8 iterations/thread, exact cover

typedef float f32x4 __attribute__((ext_vector_type(4)));
typedef int   i32x4 __attribute__((ext_vector_type(4)));

__device__ __forceinline__ float sl1_term(float o, float l, int len) {
    float d  = o - l;
    float ad = fabsf(d);
    float v  = (ad < 0.5f) ? (d * d) : (ad - 0.25f);
    float boundary = 1.0f / (float)len;   // IEEE divide; matches jnp 1/len
    return (ad >= boundary) ? v : 0.0f;
}

__global__ __launch_bounds__(BLOCK) void RegressionLoss_45440753992375_kernel(
        const float* __restrict__ outs,
        const float* __restrict__ labels,
        const int*   __restrict__ lens,
        float* __restrict__ out) {
    const f32x4* o4 = (const f32x4*)outs;
    const f32x4* l4 = (const f32x4*)labels;
    const i32x4* n4 = (const i32x4*)lens;

    // Block-contiguous: block b owns [b*BLOCK*ITERS, ...), thread strides BLOCK.
    int i = blockIdx.x * (BLOCK * ITERS) + threadIdx.x;

    // Pipeline stage 0.
    f32x4 o_c = __builtin_nontemporal_load(o4 + i);
    f32x4 l_c = __builtin_nontemporal_load(l4 + i);
    i32x4 n_c = __builtin_nontemporal_load(n4 + i);

    float acc = 0.0f;
    #pragma unroll
    for (int it = 0; it < ITERS - 1; ++it) {
        i += BLOCK;
        // Issue next-iteration nt loads BEFORE consuming current registers.
        f32x4 o_n = __builtin_nontemporal_load(o4 + i);
        f32x4 l_n = __builtin_nontemporal_load(l4 + i);
        i32x4 n_n = __builtin_nontemporal_load(n4 + i);

        acc += sl1_term(o_c.x, l_c.x, n_c.x);
        acc += sl1_term(o_c.y, l_c.y, n_c.y);
        acc += sl1_term(o_c.z, l_c.z, n_c.z);
        acc += sl1_term(o_c.w, l_c.w, n_c.w);

        o_c = o_n; l_c = l_n; n_c = n_n;
    }
    acc += sl1_term(o_c.x, l_c.x, n_c.x);
    acc += sl1_term(o_c.y, l_c.y, n_c.y);
    acc += sl1_term(o_c.z, l_c.z, n_c.z);
    acc += sl1_term(o_c.w, l_c.w, n_c.w);

    // wave-64 shuffle reduction
    #pragma unroll
    for (int off = 32; off > 0; off >>= 1)
        acc += __shfl_down(acc, off, 64);

    __shared__ float smem[BLOCK / 64];
    const int lane = threadIdx.x & 63;
    const int wid  = threadIdx.x >> 6;
    if (lane == 0) smem[wid] = acc;
    __syncthreads();
    if (threadIdx.x == 0) {
        float bsum = smem[0] + smem[1] + smem[2] + smem[3];
        atomicAdd(out, bsum);   // device-scope by default on CDNA
    }
}

extern "C" void kernel_launch(void* const* d_in, const int* in_sizes, int n_in,
                              void* d_out, int out_size, void* d_ws, size_t ws_size,
                              hipStream_t stream) {
    const float* outs   = (const float*)d_in[0];
    const float* labels = (const float*)d_in[1];
    const int*   lens   = (const int*)d_in[2];
    float* out = (float*)d_out;

    // d_out is poisoned 0xAA before every timed launch — zero it on-stream.
    hipMemsetAsync(out, 0, sizeof(float), stream);

    RegressionLoss_45440753992375_kernel<<<GRID, BLOCK, 0, stream>>>(outs, labels, lens, out);
}